// Round 10
// baseline (690.109 us; speedup 1.0000x reference)
//
#include <hip/hip_runtime.h>
#include <hip/hip_bf16.h>
#include <math.h>

#define N_ROI 512
#define N_POS 128
#define NUM_CLS 81
#define KDIM 12544          // 256 ch * 7 * 7
#define HID 1024
#define NBLK 512            // 2 blocks/CU * 256 CUs; co-residency guaranteed by
                            // __launch_bounds__(256,2) (VGPR<=256) + 17KB LDS

typedef __bf16 bf16x8 __attribute__((ext_vector_type(8)));
typedef float f32x4 __attribute__((ext_vector_type(4)));

struct Params {
  const float *P2, *P3, *P4, *P5, *rois;
  const int* label;
  const float* loc;
  const float *W1, *b1, *W2, *b2, *Wcls, *bcls, *Wloc, *bloc;
  __bf16 *xb, *W1t, *W2t, *WcT, *h1b, *h2b;
  float *h2f, *logits, *loct, *out;
  unsigned* bar;     // 7 single-use barrier counters, 64B apart, zeroed by memset
  float* part;
};

__device__ inline void gload16(const void* g, void* lds) {
  __builtin_amdgcn_global_load_lds(
      (const __attribute__((address_space(1))) void*)g,
      (__attribute__((address_space(3))) void*)lds, 16, 0, 0);
}

union __align__(16) SmU {
  float tile[64][65];
  unsigned char gemm[16384];
};

// ---------------------------------------------------------------------------
// Single-use grid barrier: all NBLK blocks co-resident by construction.
// Release fence -> arrive -> spin -> acquire fence.
// ---------------------------------------------------------------------------
__device__ inline void gbar(unsigned* cnt) {
  __syncthreads();
  if (threadIdx.x == 0) {
    __threadfence();                       // release: writeback L2 (agent scope)
    atomicAdd(cnt, 1u);
    while (atomicAdd(cnt, 0u) < NBLK) __builtin_amdgcn_s_sleep(2);
    __threadfence();                       // acquire: invalidate stale L1/L2
  }
  __syncthreads();
}

// ---------------------------------------------------------------------------
// ROI align unit: unit = (n, grp); 4 waves x 8 ch, lanes 0..48 = cells,
// 64 float2 gathers batched (R6-proven).
// ---------------------------------------------------------------------------
__device__ void roi_unit(int unit, const Params& p,
                         int* gxo, float2* gxf, int2* gyi, float2* gyf,
                         int* s_lvl, int* s_HWb) {
  int n = unit & 511;
  int grp = unit >> 9;
  int t = threadIdx.x;

  float rx1 = p.rois[n * 4 + 0], ry1 = p.rois[n * 4 + 1];
  float rx2 = p.rois[n * 4 + 2], ry2 = p.rois[n * 4 + 3];
  float area = (rx2 - rx1 + 1.0f) * (ry2 - ry1 + 1.0f);
  float lf = floorf(4.0f + log2f(sqrtf(area) / 224.0f));
  lf = fminf(fmaxf(lf, 2.0f), 5.0f);
  int lvl = (int)lf - 2;

  const float scales[4] = {0.25f, 0.125f, 0.0625f, 0.03125f};
  const int   Hs[4] = {200, 100, 50, 25};
  const int   Ws[4] = {256, 128, 64, 32};
  float sc = scales[lvl];
  int H = Hs[lvl], W = Ws[lvl];

  float bx1 = rx1 * sc, by1 = ry1 * sc;
  float bw = fmaxf(rx2 * sc - bx1, 1.0f) * (1.0f / 7.0f);
  float bh = fmaxf(ry2 * sc - by1, 1.0f) * (1.0f / 7.0f);

  if (t < 14) {
    int i = t >> 1, j = t & 1;
    float g = (float)i + 0.25f + 0.5f * (float)j;
    float px = bx1 + g * bw;
    float vx = (px > -1.0f && px < (float)W) ? 1.0f : 0.0f;
    float xx = fminf(fmaxf(px, 0.0f), (float)(W - 1));
    float x0f = floorf(xx);
    int x0 = (int)x0f;
    int xa = min(x0, W - 2);
    gxo[t] = xa * 4;
    gxf[t] = make_float2((x0 > xa) ? 1.0f : (xx - x0f), vx);
    if (t == 0) { *s_lvl = lvl; *s_HWb = H * W * 4; }
  } else if (t >= 64 && t < 78) {
    int s = t - 64;
    int i = s >> 1, j = s & 1;
    float g = (float)i + 0.25f + 0.5f * (float)j;
    float py = by1 + g * bh;
    float vy = (py > -1.0f && py < (float)H) ? 1.0f : 0.0f;
    float yy = fminf(fmaxf(py, 0.0f), (float)(H - 1));
    float y0f = floorf(yy);
    int y0 = (int)y0f;
    int y1 = min(y0 + 1, H - 1);
    gyi[s] = make_int2(y0 * W * 4, y1 * W * 4);
    gyf[s] = make_float2(yy - y0f, vy);
  }
  __syncthreads();

  int lvl_s = __builtin_amdgcn_readfirstlane(*s_lvl);
  const char* base = (const char*)(lvl_s == 0 ? p.P2 : lvl_s == 1 ? p.P3
                                   : lvl_s == 2 ? p.P4 : p.P5);
  int HWb = *s_HWb;

  int wave = t >> 6, lane = t & 63;
  if (lane < 49) {
    int oh = (lane * 37) >> 8;
    int ow = lane - oh * 7;

    int2   xo = *(const int2*)&gxo[2 * ow];
    float4 xf = *(const float4*)&gxf[2 * ow];
    int4   yi = *(const int4*)&gyi[2 * oh];
    float4 yf = *(const float4*)&gyf[2 * oh];

    int off[8];
    off[0] = yi.x + xo.x; off[1] = yi.y + xo.x;
    off[2] = yi.x + xo.y; off[3] = yi.y + xo.y;
    off[4] = yi.z + xo.x; off[5] = yi.w + xo.x;
    off[6] = yi.z + xo.y; off[7] = yi.w + xo.y;

    float w00 = yf.y * xf.y, w01 = yf.y * xf.w;
    float w10 = yf.w * xf.y, w11 = yf.w * xf.w;

    int c0 = grp * 32 + wave * 8;
    const char* bc0 = base + (size_t)c0 * HWb;

    float2 g[8][8];
#pragma unroll
    for (int ch = 0; ch < 8; ++ch) {
      const char* bcc = bc0 + (size_t)ch * HWb;
#pragma unroll
      for (int l = 0; l < 8; ++l)
        g[ch][l] = *(const float2*)(bcc + off[l]);
    }

    __bf16* outp = p.xb + (size_t)n * KDIM + (size_t)c0 * 49 + lane;
#pragma unroll
    for (int ch = 0; ch < 8; ++ch) {
      float fa, fb, s = 0.0f;
      fa = g[ch][0].x + xf.x * (g[ch][0].y - g[ch][0].x);
      fb = g[ch][1].x + xf.x * (g[ch][1].y - g[ch][1].x);
      s += (fa + yf.x * (fb - fa)) * w00;
      fa = g[ch][2].x + xf.z * (g[ch][2].y - g[ch][2].x);
      fb = g[ch][3].x + xf.z * (g[ch][3].y - g[ch][3].x);
      s += (fa + yf.x * (fb - fa)) * w01;
      fa = g[ch][4].x + xf.x * (g[ch][4].y - g[ch][4].x);
      fb = g[ch][5].x + xf.x * (g[ch][5].y - g[ch][5].x);
      s += (fa + yf.z * (fb - fa)) * w10;
      fa = g[ch][6].x + xf.z * (g[ch][6].y - g[ch][6].x);
      fb = g[ch][7].x + xf.z * (g[ch][7].y - g[ch][7].x);
      s += (fa + yf.z * (fb - fa)) * w11;
      outp[ch * 49] = (__bf16)(s * 0.25f);
    }
  }
}

// ---------------------------------------------------------------------------
// Weight transpose unit (bid in [0,3424)).
// ---------------------------------------------------------------------------
__device__ void transpose_unit(int bid, const Params& p, SmU& sm) {
  int t = threadIdx.x;
  const float* src;
  __bf16* dst;
  int R, C, bcb, brb;
  bool pad_cls = false;
  if (bid < 3136) {
    src = p.W1; dst = p.W1t; R = KDIM; C = HID;
    bcb = (bid & 15) * 64; brb = (bid >> 4) * 64;
  } else if (bid < 3392) {
    int id = bid - 3136;
    src = p.W2; dst = p.W2t; R = HID; C = HID;
    bcb = (id & 15) * 64; brb = (id >> 4) * 64;
  } else {
    int id = bid - 3392;
    src = p.Wcls; dst = p.WcT; R = HID; C = 128;
    bcb = (id >> 4) * 64; brb = (id & 15) * 64;
    pad_cls = true;
  }

  int rr = t >> 4, c4 = (t & 15) * 4;
  if (!pad_cls) {
#pragma unroll
    for (int q = 0; q < 4; ++q) {
      int r = q * 16 + rr;
      f32x4 v = *(const f32x4*)&src[(size_t)(brb + r) * C + bcb + c4];
      sm.tile[r][c4] = v.x; sm.tile[r][c4 + 1] = v.y;
      sm.tile[r][c4 + 2] = v.z; sm.tile[r][c4 + 3] = v.w;
    }
  } else {
#pragma unroll
    for (int q = 0; q < 4; ++q) {
      int r = q * 16 + rr;
#pragma unroll
      for (int i = 0; i < 4; ++i) {
        int j = bcb + c4 + i;
        sm.tile[r][c4 + i] =
            (j < NUM_CLS) ? src[(size_t)(brb + r) * NUM_CLS + j] : 0.0f;
      }
    }
  }
  __syncthreads();
#pragma unroll
  for (int q = 0; q < 2; ++q) {
    int group = t + 256 * q;
    int c = group >> 3;
    int r0 = (group & 7) * 8;
    bf16x8 o;
#pragma unroll
    for (int j = 0; j < 8; ++j) o[j] = (__bf16)sm.tile[r0 + j][c];
    *(bf16x8*)&dst[(size_t)(bcb + c) * R + brb + r0] = o;
  }
}

// ---------------------------------------------------------------------------
// m97-style GEMM tile with split-K (block-uniform arguments).
// ---------------------------------------------------------------------------
__device__ void gemm_tile(const __bf16* A, const __bf16* Bt, float* part,
                          int M, int N, int K, int tm, int tn, int z,
                          int chunk, SmU& sm) {
  unsigned char* As = sm.gemm;
  unsigned char* Bs = sm.gemm + 8192;

  int t = threadIdx.x;
  int wave = t >> 6;
  int lane = t & 63;
  int fr = lane & 15, q = lane >> 4;
  int bm = tm * 128, bn = tn * 128;
  int wm = (wave >> 1) * 64, wn = (wave & 1) * 64;

  int kbeg = z * chunk;
  int kend = min(K, kbeg + chunk);

  int qsrc = ((t & 3) - ((t >> 3) & 3)) & 3;
  const __bf16* a0 = A + (size_t)(bm + (t >> 2)) * K + kbeg + qsrc * 8;
  const __bf16* a1 = a0 + (size_t)64 * K;
  const __bf16* b0 = Bt + (size_t)(bn + (t >> 2)) * K + kbeg + qsrc * 8;
  const __bf16* b1 = b0 + (size_t)64 * K;
  unsigned char* AsW = As + wave * 1024;
  unsigned char* BsW = Bs + wave * 1024;

  int sA = ((q + (fr >> 1)) & 3) * 16;

  f32x4 acc[4][4];
#pragma unroll
  for (int i = 0; i < 4; ++i)
#pragma unroll
    for (int j = 0; j < 4; ++j) acc[i][j] = (f32x4){0.f, 0.f, 0.f, 0.f};

  for (int k0 = kbeg; k0 < kend; k0 += 32) {
    __syncthreads();
    gload16(a0, AsW);
    gload16(a1, AsW + 4096);
    gload16(b0, BsW);
    gload16(b1, BsW + 4096);
    a0 += 32; a1 += 32; b0 += 32; b1 += 32;
    __syncthreads();

    bf16x8 af[4], bfr[4];
#pragma unroll
    for (int i = 0; i < 4; ++i)
      af[i] = *(const bf16x8*)(As + (wm + 16 * i + fr) * 64 + sA);
#pragma unroll
    for (int j = 0; j < 4; ++j)
      bfr[j] = *(const bf16x8*)(Bs + (wn + 16 * j + fr) * 64 + sA);
#pragma unroll
    for (int i = 0; i < 4; ++i)
#pragma unroll
      for (int j = 0; j < 4; ++j)
        acc[i][j] = __builtin_amdgcn_mfma_f32_16x16x32_bf16(af[i], bfr[j],
                                                            acc[i][j], 0, 0, 0);
  }

  float* P = part + (size_t)z * M * N;
#pragma unroll
  for (int i = 0; i < 4; ++i) {
#pragma unroll
    for (int j = 0; j < 4; ++j) {
      int row0 = bm + wm + 16 * i + q * 4;
      int col = bn + wn + 16 * j + fr;
#pragma unroll
      for (int r = 0; r < 4; ++r)
        P[(size_t)(row0 + r) * N + col] = acc[i][j][r];
    }
  }
}

// ---------------------------------------------------------------------------
__device__ void reduce_unit(int qidx, const float* part, int S, int MN,
                            int Nmask, const float* bias, int bias_n, int relu,
                            float* outf, __bf16* outb) {
  int i4 = qidx * 4;
  if (i4 >= MN) return;
  f32x4 s = {0.f, 0.f, 0.f, 0.f};
  for (int z = 0; z < S; ++z) {
    f32x4 v = *(const f32x4*)&part[(size_t)z * MN + i4];
    s.x += v.x; s.y += v.y; s.z += v.z; s.w += v.w;
  }
  int col = i4 & Nmask;
  float r[4] = {s.x, s.y, s.z, s.w};
#pragma unroll
  for (int j = 0; j < 4; ++j) {
    float b = (col + j < bias_n) ? bias[col + j] : 0.0f;
    float v = r[j] + b;
    if (relu) v = fmaxf(v, 0.0f);
    r[j] = v;
  }
  if (outf) {
    f32x4 o = {r[0], r[1], r[2], r[3]};
    *(f32x4*)&outf[i4] = o;
  }
  if (outb) {
    __bf16 o[4] = {(__bf16)r[0], (__bf16)r[1], (__bf16)r[2], (__bf16)r[3]};
    *(double*)&outb[i4] = *(double*)o;
  }
}

// ---------------------------------------------------------------------------
__device__ void loc_unit(int n, const Params& p) {
  int d = threadIdx.x >> 6;
  int lane = threadIdx.x & 63;
  int lab = p.label[n];
  const float* h = p.h2f + (size_t)n * HID;
  const float* w = p.Wloc + (size_t)lab * 4 + d;
  float s = 0.0f;
#pragma unroll
  for (int i = 0; i < 16; ++i) {
    int k = lane + i * 64;
    s += h[k] * w[(size_t)k * (NUM_CLS * 4)];
  }
#pragma unroll
  for (int off = 32; off > 0; off >>= 1) s += __shfl_down(s, off);
  if (lane == 0) p.loct[n * 4 + d] = s + p.bloc[lab * 4 + d];
}

// ---------------------------------------------------------------------------
__device__ void loss_unit(const Params& p) {
  __shared__ float red[4];
  int t = threadIdx.x;
  float v = 0.0f;
#pragma unroll
  for (int rr = 0; rr < 2; ++rr) {
    int r = t + rr * 256;
    const float* row = p.logits + (size_t)r * 128;
    float m = -1e30f;
    for (int j = 0; j < NUM_CLS; ++j) m = fmaxf(m, row[j]);
    float se = 0.0f;
    for (int j = 0; j < NUM_CLS; ++j) se += expf(row[j] - m);
    v += (m + logf(se)) - row[p.label[r]];
    float a = fabsf(p.loct[r] - p.loc[r]);
    v += (a < 1.0f) ? 0.5f * a * a : a - 0.5f;
  }
#pragma unroll
  for (int off = 32; off > 0; off >>= 1) v += __shfl_down(v, off);
  if ((t & 63) == 0) red[t >> 6] = v;
  __syncthreads();
  if (t == 0)
    p.out[0] = (red[0] + red[1] + red[2] + red[3]) * (1.0f / (float)N_ROI);
}

// ---------------------------------------------------------------------------
__global__ __launch_bounds__(256, 2) void mega_kernel(Params p) {
  int b = blockIdx.x;
  int t = threadIdx.x;

  __shared__ SmU sm;
  __shared__ int    gxo[14];
  __shared__ float2 gxf[14];
  __shared__ int2   gyi[14];
  __shared__ float2 gyf[14];
  __shared__ int    s_lvl, s_HWb;

  // stage 0: roi (0..4095) + weight transposes (4096..7519)
  for (int u = b; u < 7520; u += NBLK) {
    if (u < 4096)
      roi_unit(u, p, gxo, gxf, gyi, gyf, &s_lvl, &s_HWb);
    else
      transpose_unit(u - 4096, p, sm);
    __syncthreads();
  }
  gbar(p.bar + 0);

  // stage 1: FC1 [512,12544]@[12544,1024], split-K 16 -> 512 tile-units
  for (int u = b; u < 512; u += NBLK)
    gemm_tile(p.xb, p.W1t, p.part, N_ROI, HID, KDIM, u >> 7, (u >> 4) & 7,
              u & 15, 800, sm);
  gbar(p.bar + 16);

  // stage 2: reduce1 -> h1b (bf16, relu)
  for (int q = b * 256 + t; q < (N_ROI * HID) / 4; q += NBLK * 256)
    reduce_unit(q, p.part, 16, N_ROI * HID, HID - 1, p.b1, HID, 1, nullptr,
                p.h1b);
  gbar(p.bar + 32);

  // stage 3: FC2 [512,1024]@[1024,1024], split-K 8 -> 256 tile-units
  for (int u = b; u < 256; u += NBLK)
    gemm_tile(p.h1b, p.W2t, p.part, N_ROI, HID, HID, u >> 6, (u >> 3) & 7,
              u & 7, 128, sm);
  gbar(p.bar + 48);

  // stage 4: reduce2 -> h2f + h2b (relu)
  for (int q = b * 256 + t; q < (N_ROI * HID) / 4; q += NBLK * 256)
    reduce_unit(q, p.part, 8, N_ROI * HID, HID - 1, p.b2, HID, 1, p.h2f,
                p.h2b);
  gbar(p.bar + 64);

  // stage 5: cls GEMM (64 tile-units) || loc head (128 units)
  for (int u = b; u < 64 + N_POS; u += NBLK) {
    if (u < 64)
      gemm_tile(p.h2b, p.WcT, p.part, N_ROI, 128, HID, u >> 4, 0, u & 15, 64,
                sm);
    else
      loc_unit(u - 64, p);
    __syncthreads();
  }
  gbar(p.bar + 80);

  // stage 6: reduce3 -> logits (fp32, row stride 128)
  for (int q = b * 256 + t; q < (N_ROI * 128) / 4; q += NBLK * 256)
    reduce_unit(q, p.part, 16, N_ROI * 128, 127, p.bcls, NUM_CLS, 0, p.logits,
                nullptr);
  gbar(p.bar + 96);

  // stage 7: loss
  if (b == 0) loss_unit(p);
}

// ---------------------------------------------------------------------------
extern "C" void kernel_launch(void* const* d_in, const int* in_sizes, int n_in,
                              void* d_out, int out_size, void* d_ws, size_t ws_size,
                              hipStream_t stream) {
  Params p;
  p.P2   = (const float*)d_in[0];
  p.P3   = (const float*)d_in[1];
  p.P4   = (const float*)d_in[2];
  p.P5   = (const float*)d_in[3];
  p.rois = (const float*)d_in[4];
  p.label= (const int*)d_in[5];
  p.loc  = (const float*)d_in[6];
  p.W1   = (const float*)d_in[7];
  p.b1   = (const float*)d_in[8];
  p.W2   = (const float*)d_in[9];
  p.b2   = (const float*)d_in[10];
  p.Wcls = (const float*)d_in[11];
  p.bcls = (const float*)d_in[12];
  p.Wloc = (const float*)d_in[13];
  p.bloc = (const float*)d_in[14];
  p.out  = (float*)d_out;

  char* w = (char*)d_ws;
  p.xb  = (__bf16*)w;  w += (size_t)N_ROI * KDIM * 2;
  p.W1t = (__bf16*)w;  w += (size_t)KDIM * HID * 2;
  p.W2t = (__bf16*)w;  w += (size_t)HID * HID * 2;
  p.WcT = (__bf16*)w;  w += (size_t)128 * HID * 2;
  p.h1b = (__bf16*)w;  w += (size_t)N_ROI * HID * 2;
  p.h2b = (__bf16*)w;  w += (size_t)N_ROI * HID * 2;
  p.h2f = (float*)w;   w += (size_t)N_ROI * HID * 4;
  p.logits = (float*)w; w += (size_t)N_ROI * 128 * 4;
  p.loct = (float*)w;  w += (size_t)N_ROI * 4;
  p.bar  = (unsigned*)w; w += 512;          // 7 counters, 64B apart
  p.part = (float*)w;                        // 16 * 512 * 1024 * 4 = 32 MB

  hipMemsetAsync(p.bar, 0, 512, stream);
  mega_kernel<<<NBLK, 256, 0, stream>>>(p);
}